// Round 5
// baseline (255.942 us; speedup 1.0000x reference)
//
#include <hip/hip_runtime.h>
#include <hip/hip_bf16.h>
#include <math.h>

// VOCAB=50000, EMBED=256, MAXLEN=512, UNITS=32, F1=16, BATCH=512.
#define TT 512
#define BB 512
#define EE 256
#define UU 32
#define FF1 16

__device__ __forceinline__ void fma4(float4& a, float s, const float4& v) {
    a.x = fmaf(s, v.x, a.x); a.y = fmaf(s, v.y, a.y);
    a.z = fmaf(s, v.z, a.z); a.w = fmaf(s, v.w, a.w);
}

// tanh(x) = 1 - 2/(e^{2x}+1), branch-free (5 VALU instrs).
__device__ __forceinline__ float fast_tanh(float x) {
    float e = __builtin_amdgcn_exp2f(x * 2.8853900817779268f);  // e^{2x}
    float r = __builtin_amdgcn_rcpf(e + 1.0f);
    return fmaf(-2.0f, r, 1.0f);
}

__device__ __forceinline__ float rdlane(float v, int lane) {
    return __int_as_float(__builtin_amdgcn_readlane(__float_as_int(v), lane));
}

// ---------------------------------------------------------------------------
// Kernel A1: k-split partial projection.
// Thread g = r*4 + c computes PP[g][u] = emb[r][64c .. 64c+63] @ Wx-chunk.
// 200000 threads -> 782 blocks -> ~3 blocks/CU (12 waves/CU, latency hiding).
// emb reads: lane-adjacent threads cover (r, r, r, r, r+1,...) x 256-B chunks
// -> coalesced at wave granularity. Whole 64-float chunk preloaded into 16
// float4 regs: ONE vmcnt wait per thread, no per-iteration memory stalls.
// Wx staged in LDS, read as wave-uniform broadcast b128 (conflict-free).
// PP writes are thread-linear -> perfectly coalesced.
// ---------------------------------------------------------------------------
__global__ __launch_bounds__(256, 3) void proj_part(
    const float* __restrict__ emb, const float* __restrict__ Wx,
    float* __restrict__ PP, int nrows)
{
    __shared__ float sWx[EE * UU];   // 32 KB

    {   // cooperative stage of Wx into LDS
        const float4* src = (const float4*)Wx;
        float4* dst = (float4*)sWx;
        #pragma unroll
        for (int i = 0; i < 8; ++i)
            dst[threadIdx.x + 256 * i] = src[threadIdx.x + 256 * i];
    }
    __syncthreads();

    const int g = blockIdx.x * 256 + threadIdx.x;
    const int c = g & 3;
    const int r = g >> 2;
    if (r >= nrows) return;

    // preload this thread's 64-float chunk (16 float4, all in flight at once)
    const float4* e = (const float4*)(emb + (size_t)r * EE + c * 64);
    float4 x[16];
    #pragma unroll
    for (int i = 0; i < 16; ++i) x[i] = e[i];

    float4 acc[8];
    #pragma unroll
    for (int j = 0; j < 8; ++j) acc[j] = make_float4(0.f, 0.f, 0.f, 0.f);

    const float4* wbase = (const float4*)sWx + (c * 64) * 8;  // chunk rows
    #pragma unroll
    for (int k4 = 0; k4 < 16; ++k4) {        // 4 k-values per iteration
        float4 xv = x[k4];
        const float4* w = wbase + k4 * 32;
        #pragma unroll
        for (int j4 = 0; j4 < 8; ++j4) {
            float4 wa = w[j4];
            float4 wb = w[8 + j4];
            float4 wc = w[16 + j4];
            float4 wd = w[24 + j4];
            fma4(acc[j4], xv.x, wa); fma4(acc[j4], xv.y, wb);
            fma4(acc[j4], xv.z, wc); fma4(acc[j4], xv.w, wd);
        }
    }

    float4* o = (float4*)PP + (size_t)g * 8;  // thread-linear, coalesced
    #pragma unroll
    for (int j4 = 0; j4 < 8; ++j4) o[j4] = acc[j4];
}

// ---------------------------------------------------------------------------
// Kernel A2: P[r][u] = sum_c PP[r*4+c][u] + bias[u].  Pure streaming.
// ---------------------------------------------------------------------------
__global__ __launch_bounds__(256) void proj_reduce(
    const float* __restrict__ PPf, const float* __restrict__ bias,
    float* __restrict__ P, int nrows)
{
    const int i4 = blockIdx.x * 256 + threadIdx.x;   // float4 index into P
    if (i4 >= nrows * 8) return;
    const int r  = i4 >> 3;
    const int u4 = i4 & 7;

    const float4* PP4 = (const float4*)PPf;
    float4 s0 = PP4[(size_t)(r * 4 + 0) * 8 + u4];
    float4 s1 = PP4[(size_t)(r * 4 + 1) * 8 + u4];
    float4 s2 = PP4[(size_t)(r * 4 + 2) * 8 + u4];
    float4 s3 = PP4[(size_t)(r * 4 + 3) * 8 + u4];
    float4 bq = ((const float4*)bias)[u4];

    float4 o;
    o.x = (s0.x + s1.x) + (s2.x + s3.x) + bq.x;
    o.y = (s0.y + s1.y) + (s2.y + s3.y) + bq.y;
    o.z = (s0.z + s1.z) + (s2.z + s3.z) + bq.z;
    o.w = (s0.w + s1.w) + (s2.w + s3.w) + bq.w;
    ((float4*)P)[i4] = o;
}

// ---------------------------------------------------------------------------
// Kernel B: h_t = tanh(P[tok[b,t]] + h_{t-1} @ Wh); fused heads + sigmoid.
// One batch row per 64-lane wave (both halves duplicate; no divergence).
// h broadcast via v_readlane, ALL 32 hoisted before the FMA block
// (amortizes the VALU->SGPR hazard wait states to ~zero).
// P prefetched 8 steps deep (register ring): slack ~8 x step >> L3 latency.
// ---------------------------------------------------------------------------
__global__ __launch_bounds__(64) void scan_heads(
    const int* __restrict__ tokens, const float* __restrict__ P,
    const float* __restrict__ Wh,
    const float* __restrict__ W1, const float* __restrict__ b1,
    const float* __restrict__ W2, const float* __restrict__ b2,
    float* __restrict__ out)
{
    const int u = threadIdx.x & 31;
    const int b = blockIdx.x;

    // wh[k] = Wh[k][u] : this lane's column of the recurrent matrix
    float wh[UU];
    #pragma unroll
    for (int k = 0; k < UU; ++k) wh[k] = Wh[k * UU + u];

    const int* trow = tokens + b * TT;

    // 8-deep software pipeline: xr[j] = x(t+j); tk[j] = token(t+8+j)
    float xr[8]; int tk[8];
    #pragma unroll
    for (int j = 0; j < 8; ++j) {
        xr[j] = P[(size_t)trow[j] * UU + u];
        tk[j] = trow[8 + j];
    }

    float h = 0.f;

    for (int t = 0; t < TT; t += 8) {
        #pragma unroll
        for (int j = 0; j < 8; ++j) {
            // prefetch x(t+j+8); token(t+j+16) (&-wrap: harmless at tail)
            float xn = P[(size_t)tk[j] * UU + u];
            tk[j] = trow[(t + 16 + j) & (TT - 1)];

            // hoist ALL broadcasts first (32 readlanes -> SGPRs)
            float hb[UU];
            #pragma unroll
            for (int k = 0; k < UU; ++k) hb[k] = rdlane(h, k);

            // z_u = x_u + sum_k h_k * wh[k] : 4 independent 8-FMA chains
            float a0 = xr[j], a1 = 0.f, a2 = 0.f, a3 = 0.f;
            #pragma unroll
            for (int k = 0; k < UU; k += 4) {
                a0 = fmaf(hb[k],     wh[k],     a0);
                a1 = fmaf(hb[k + 1], wh[k + 1], a1);
                a2 = fmaf(hb[k + 2], wh[k + 2], a2);
                a3 = fmaf(hb[k + 3], wh[k + 3], a3);
            }
            h = fast_tanh((a0 + a1) + (a2 + a3));
            xr[j] = xn;
        }
    }

    // ---- fused heads (once; readlane-only, no LDS) ----
    const int j = threadIdx.x & 15;
    float s = b1[j];
    #pragma unroll
    for (int k = 0; k < UU; ++k) {
        float hk = rdlane(h, k);
        s = fmaf(hk, W1[k * FF1 + j], s);
    }
    float z = b2[0];
    #pragma unroll
    for (int jj = 0; jj < FF1; ++jj) {
        float yj = rdlane(s, jj);
        z = fmaf(yj, W2[jj], z);
    }
    if (threadIdx.x == 0) {
        float e = __builtin_amdgcn_exp2f(-z * 1.4426950408889634f); // e^{-z}
        out[b] = __builtin_amdgcn_rcpf(1.0f + e);
    }
}

// ---------------------------------------------------------------------------
extern "C" void kernel_launch(void* const* d_in, const int* in_sizes, int n_in,
                              void* d_out, int out_size, void* d_ws, size_t ws_size,
                              hipStream_t stream) {
    const int*   tokens = (const int*)  d_in[0];
    const float* emb    = (const float*)d_in[1];
    const float* Wx     = (const float*)d_in[2];
    const float* Wh     = (const float*)d_in[3];
    const float* bias   = (const float*)d_in[4];
    const float* W1     = (const float*)d_in[5];
    const float* b1     = (const float*)d_in[6];
    const float* W2     = (const float*)d_in[7];
    const float* b2     = (const float*)d_in[8];
    float* out = (float*)d_out;

    const int vocab = in_sizes[1] / EE;               // 50000
    float* P  = (float*)d_ws;                         // vocab*32*4   = 6.4 MB
    float* PP = (float*)d_ws + (size_t)vocab * UU;    // vocab*4*32*4 = 25.6 MB

    // A1: 4 k-chunks x 50000 rows = 200000 threads -> 782 blocks
    proj_part<<<dim3((vocab * 4 + 255) / 256), dim3(256), 0, stream>>>(
        emb, Wx, PP, vocab);

    // A2: 400000 float4 -> 1563 blocks
    proj_reduce<<<dim3((vocab * 8 + 255) / 256), dim3(256), 0, stream>>>(
        PP, bias, P, vocab);

    // B: 1 batch row per wave -> 512 blocks x 64 threads
    scan_heads<<<dim3(BB), dim3(64), 0, stream>>>(
        tokens, P, Wh, W1, b1, W2, b2, out);
}

// Round 6
// 192.460 us; speedup vs baseline: 1.3298x; 1.3298x over previous
//
#include <hip/hip_runtime.h>
#include <hip/hip_bf16.h>
#include <math.h>

// VOCAB=50000, EMBED=256, MAXLEN=512, UNITS=32, F1=16, BATCH=512.
#define TT 512
#define BB 512
#define EE 256
#define UU 32
#define FF1 16

__device__ __forceinline__ void fma4(float4& a, float s, const float4& v) {
    a.x = fmaf(s, v.x, a.x); a.y = fmaf(s, v.y, a.y);
    a.z = fmaf(s, v.z, a.z); a.w = fmaf(s, v.w, a.w);
}

// tanh(x) = 1 - 2/(e^{2x}+1), branch-free (exp2+rcp HW approx).
__device__ __forceinline__ float fast_tanh(float x) {
    float e = __builtin_amdgcn_exp2f(x * 2.8853900817779268f);  // e^{2x}
    float r = __builtin_amdgcn_rcpf(e + 1.0f);
    return fmaf(-2.0f, r, 1.0f);
}

__device__ __forceinline__ float rdlane(float v, int lane) {
    return __int_as_float(__builtin_amdgcn_readlane(__float_as_int(v), lane));
}

// ---------------------------------------------------------------------------
// Kernel A: P[r][u] = emb[r] @ Wx[:,u] + bias[u]  — register-tiled GEMV,
// NO LDS (prior rounds were LDS-broadcast-pipe bound at ~130 us).
// Wave covers 32 rows. lane = rg*8+ug: rg(0..7) picks a 4-row group,
// ug(0..7) picks a 4-unit quad. Per lane: 4 rows x 4 units in registers.
// Per k4-iter loads: 4 x-quads (8 distinct 16-B segs/instr, L1-friendly) +
// 4 Wx-quads (contiguous 128 B/instr, L2-resident 32 KB) vs 16 fma4 —
// VMEM-issue and VALU balanced. Double-buffered (A/B) 1-iter prefetch.
// ---------------------------------------------------------------------------
__global__ __launch_bounds__(64) void proj_gemv(
    const float* __restrict__ emb, const float* __restrict__ Wx,
    const float* __restrict__ bias, float* __restrict__ P, int nrows)
{
    const int lane = threadIdx.x;
    const int ug = lane & 7;
    const int rg = lane >> 3;
    const int r0 = blockIdx.x * 32 + rg * 4;

    const float4* xp[4];
    #pragma unroll
    for (int i = 0; i < 4; ++i) {
        int r = r0 + i; if (r > nrows - 1) r = nrows - 1;   // clamp loads
        xp[i] = (const float4*)(emb + (size_t)r * EE);
    }
    const float4* wxp = (const float4*)Wx + ug;   // row k -> wxp[k*8]

    float4 acc[4];
    #pragma unroll
    for (int i = 0; i < 4; ++i) acc[i] = make_float4(0.f, 0.f, 0.f, 0.f);

    float4 xqA[4], xqB[4], wqA[4], wqB[4];
    #pragma unroll
    for (int i = 0; i < 4; ++i) xqA[i] = xp[i][0];
    #pragma unroll
    for (int kk = 0; kk < 4; ++kk) wqA[kk] = wxp[kk * 8];

    for (int k4 = 0; k4 < 64; k4 += 2) {
        // prefetch odd iter (k4+1)
        #pragma unroll
        for (int i = 0; i < 4; ++i) xqB[i] = xp[i][k4 + 1];
        #pragma unroll
        for (int kk = 0; kk < 4; ++kk) wqB[kk] = wxp[(4 * (k4 + 1) + kk) * 8];
        // compute even iter (k4)
        #pragma unroll
        for (int i = 0; i < 4; ++i) {
            fma4(acc[i], xqA[i].x, wqA[0]);
            fma4(acc[i], xqA[i].y, wqA[1]);
            fma4(acc[i], xqA[i].z, wqA[2]);
            fma4(acc[i], xqA[i].w, wqA[3]);
        }
        // prefetch next even iter (wraps to 0 on last pass — harmless)
        const int kn = (k4 + 2) & 63;
        #pragma unroll
        for (int i = 0; i < 4; ++i) xqA[i] = xp[i][kn];
        #pragma unroll
        for (int kk = 0; kk < 4; ++kk) wqA[kk] = wxp[(4 * kn + kk) * 8];
        // compute odd iter (k4+1)
        #pragma unroll
        for (int i = 0; i < 4; ++i) {
            fma4(acc[i], xqB[i].x, wqB[0]);
            fma4(acc[i], xqB[i].y, wqB[1]);
            fma4(acc[i], xqB[i].z, wqB[2]);
            fma4(acc[i], xqB[i].w, wqB[3]);
        }
    }

    const float4 bq = ((const float4*)bias)[ug];
    #pragma unroll
    for (int i = 0; i < 4; ++i) {
        const int r = r0 + i;
        if (r < nrows) {
            float4 o = acc[i];
            o.x += bq.x; o.y += bq.y; o.z += bq.z; o.w += bq.w;
            *((float4*)(P + (size_t)r * UU) + ug) = o;
        }
    }
}

// ---------------------------------------------------------------------------
// Kernel B: h_t = tanh(x_t + h_{t-1} @ Wh); fused heads + sigmoid.
// One batch row per 64-lane wave. ALL 512 x-vectors (64 KB) are gathered
// into LDS upfront via global_load_lds width=16 (per-lane gather address;
// LDS dest = uniform base + lane*16 matches the row layout exactly).
// The scan loop has ZERO global accesses: 1 prefetched ds_read_b32 +
// interleaved readlane/FMA (round-4 structure) + fast tanh.
// LDS 64 KB, 1-wave blocks -> 2 blocks/CU = 512 waves, exact fit.
// ---------------------------------------------------------------------------
__global__ __launch_bounds__(64) void scan_heads(
    const int* __restrict__ tokens, const float* __restrict__ P,
    const float* __restrict__ Wh,
    const float* __restrict__ W1, const float* __restrict__ b1,
    const float* __restrict__ W2, const float* __restrict__ b2,
    float* __restrict__ out)
{
    __shared__ float xs[TT * UU];      // 512 rows x 128 B = 64 KB

    const int L = threadIdx.x;
    const int u = L & 31;
    const int b = blockIdx.x;
    const int* trow = tokens + b * TT;

    // wh[k] = Wh[k][u] : this lane's column of the recurrent matrix
    float wh[UU];
    #pragma unroll
    for (int k = 0; k < UU; ++k) wh[k] = Wh[k * UU + u];

    // ---- gather phase: 64 global_load_lds instrs, 8 tokens each ----
    // instr (c,i): token T = c*64 + i*8 + (L>>3); lane writes T's row chunk
    // (L&7)*16 B to LDS at (c*64+i*8)*128 + L*16  ==  T*128 + (L&7)*16. 
    const int sub = L >> 3;            // token-within-group
    const int q   = L & 7;             // 16-B chunk within the 128-B row
    for (int c = 0; c < 8; ++c) {
        int tk8[8];
        #pragma unroll
        for (int i = 0; i < 8; ++i)
            tk8[i] = trow[c * 64 + i * 8 + sub];
        #pragma unroll
        for (int i = 0; i < 8; ++i) {
            const float* src = P + (size_t)tk8[i] * UU + q * 4;
            float* dst = xs + (c * 64 + i * 8) * UU;    // wave-uniform base
            __builtin_amdgcn_global_load_lds(
                (const __attribute__((address_space(1))) void*)src,
                (__attribute__((address_space(3))) void*)dst, 16, 0, 0);
        }
    }
    __syncthreads();   // drains vmcnt: all LDS rows resident

    // ---- scan: pure LDS + VALU ----
    float xr[4];
    #pragma unroll
    for (int j = 0; j < 4; ++j) xr[j] = xs[j * UU + u];

    float h = 0.f;

    for (int t = 0; t < TT; t += 4) {
        #pragma unroll
        for (int j = 0; j < 4; ++j) {
            float xn = xs[((t + 4 + j) & (TT - 1)) * UU + u];  // prefetch

            float a0 = xr[j], a1 = 0.f, a2 = 0.f, a3 = 0.f;
            #pragma unroll
            for (int k = 0; k < UU; k += 4) {
                float h0 = rdlane(h, k);
                float h1 = rdlane(h, k + 1);
                float h2 = rdlane(h, k + 2);
                float h3 = rdlane(h, k + 3);
                a0 = fmaf(h0, wh[k],     a0);
                a1 = fmaf(h1, wh[k + 1], a1);
                a2 = fmaf(h2, wh[k + 2], a2);
                a3 = fmaf(h3, wh[k + 3], a3);
            }
            h = fast_tanh((a0 + a1) + (a2 + a3));
            xr[j] = xn;
        }
    }

    // ---- fused heads (once; readlane-only) ----
    const int j = threadIdx.x & 15;
    float s = b1[j];
    #pragma unroll
    for (int k = 0; k < UU; ++k) {
        float hk = rdlane(h, k);
        s = fmaf(hk, W1[k * FF1 + j], s);
    }
    float z = b2[0];
    #pragma unroll
    for (int jj = 0; jj < FF1; ++jj) {
        float yj = rdlane(s, jj);
        z = fmaf(yj, W2[jj], z);
    }
    if (threadIdx.x == 0) {
        float e = __builtin_amdgcn_exp2f(-z * 1.4426950408889634f); // e^{-z}
        out[b] = __builtin_amdgcn_rcpf(1.0f + e);
    }
}

// ---------------------------------------------------------------------------
extern "C" void kernel_launch(void* const* d_in, const int* in_sizes, int n_in,
                              void* d_out, int out_size, void* d_ws, size_t ws_size,
                              hipStream_t stream) {
    const int*   tokens = (const int*)  d_in[0];
    const float* emb    = (const float*)d_in[1];
    const float* Wx     = (const float*)d_in[2];
    const float* Wh     = (const float*)d_in[3];
    const float* bias   = (const float*)d_in[4];
    const float* W1     = (const float*)d_in[5];
    const float* b1     = (const float*)d_in[6];
    const float* W2     = (const float*)d_in[7];
    const float* b2     = (const float*)d_in[8];
    float* out = (float*)d_out;

    const int vocab = in_sizes[1] / EE;        // 50000
    float* P = (float*)d_ws;                   // vocab*32*4 = 6.4 MB

    // A: 32 rows per 64-thread block -> 1563 blocks (~6 waves/CU)
    proj_gemv<<<dim3((vocab + 31) / 32), dim3(64), 0, stream>>>(
        emb, Wx, bias, P, vocab);

    // B: 1 batch row per wave -> 512 blocks x 64 threads (2 blocks/CU)
    scan_heads<<<dim3(BB), dim3(64), 0, stream>>>(
        tokens, P, Wh, W1, b1, W2, b2, out);
}